// Round 7
// baseline (3428.441 us; speedup 1.0000x reference)
//
#include <hip/hip_runtime.h>
#include <math.h>

#define D4 20736
#define ST 15    // k123 LDS row stride (c32): 120B -> spectator stride 180 c32 (8-bank offset)
#define SST 180  // 12*ST
#define KP 17    // k01 LDS row stride (c32): 136B

typedef float2 c32;

__device__ __forceinline__ c32 cmul(c32 a, c32 b) {
  return make_float2(a.x * b.x - a.y * b.y, a.x * b.y + a.y * b.x);
}
__device__ __forceinline__ c32 cfma(c32 a, c32 b, c32 acc) {
  acc.x = fmaf(a.x, b.x, fmaf(-a.y, b.y, acc.x));
  acc.y = fmaf(a.x, b.y, fmaf(a.y, b.x, acc.y));
  return acc;
}
#define CZERO make_float2(0.f, 0.f)

// sector offsets: secoff[N] = sum_{n<N} sz(n)^2, sz(n)=min(n,22-n,11)+1
__constant__ int d_secoff[24] = {0,1,5,14,30,55,91,140,204,285,385,506,650,
                                 771,871,952,1016,1065,1101,1126,1142,1151,1155,1156};

struct RM { int goff, sz, a0, da, r0, dr; };
// metadata for output pattern-row r=(i,j): sector walk bases/steps.
// a0/da: cross-pattern walk in ST-flat units (pass bs23); r0/dr: row walk.
// Down-sectors iterate descending (gates stored column-reversed by prep_bs).
__device__ __forceinline__ RM rmeta(int r) {
  const int i = r / 12, j = r - 12 * i, N = i + j;
  const bool up = (N <= 11);
  RM m;
  m.sz = (up ? N : 22 - N) + 1;
  const int lo = up ? 0 : (N - 11);
  m.goff = d_secoff[N] + (i - lo) * m.sz;   // table lookup (R5-proven)
  m.a0 = up ? N : (154 + N);      // 15*p2 + p3 at t=0
  m.da = up ? (ST - 1) : -(ST - 1);
  m.r0 = up ? N : (121 + N);      // 11*p + N at t=0
  m.dr = up ? 11 : -11;
  return m;
}

// ---------------- small matrix expm (LDS, 64-thread block) ----------------
__device__ void small_expm(c32* A, c32* S, c32* P, c32* T, float* red, int sz, int tid) {
  const int n2 = sz * sz;
  if (tid < sz) {
    float s = 0.f;
    for (int j = 0; j < sz; ++j) { c32 v = A[tid * sz + j]; s += sqrtf(fmaf(v.x, v.x, v.y * v.y)); }
    red[tid] = s;
  }
  __syncthreads();
  float nrm = 0.f;
  for (int i = 0; i < sz; ++i) nrm = fmaxf(nrm, red[i]);
  int sp = 0;
  while (nrm > 0.35f && sp < 24) { nrm *= 0.5f; ++sp; }
  const float scale = ldexpf(1.f, -sp);
  for (int e = tid; e < n2; e += 64) { A[e].x *= scale; A[e].y *= scale; }
  __syncthreads();
  for (int e = tid; e < n2; e += 64) {
    c32 a = A[e];
    P[e] = a;
    if ((e / sz) == (e % sz)) a.x += 1.f;
    S[e] = a;
  }
  __syncthreads();
  for (int k = 2; k <= 12; ++k) {
    const float inv = 1.f / (float)k;
    for (int e = tid; e < n2; e += 64) {
      int i = e / sz, j = e - i * sz;
      c32 acc = CZERO;
      for (int q = 0; q < sz; ++q) acc = cfma(P[i * sz + q], A[q * sz + j], acc);
      acc.x *= inv; acc.y *= inv;
      T[e] = acc;
    }
    __syncthreads();
    for (int e = tid; e < n2; e += 64) {
      c32 t = T[e];
      P[e] = t;
      S[e].x += t.x; S[e].y += t.y;
    }
    __syncthreads();
  }
  for (int q = 0; q < sp; ++q) {
    for (int e = tid; e < n2; e += 64) {
      int i = e / sz, j = e - i * sz;
      c32 acc = CZERO;
      for (int w = 0; w < sz; ++w) acc = cfma(S[i * sz + w], S[w * sz + j], acc);
      T[e] = acc;
    }
    __syncthreads();
    for (int e = tid; e < n2; e += 64) S[e] = T[e];
    __syncthreads();
  }
}

// ---------------- prep: per-batch displacement encoding (store col 0) ----------------
__global__ __launch_bounds__(64) void prep_disp(const float* __restrict__ x, c32* __restrict__ c0) {
  __shared__ c32 A[144], S[144], P[144], T[144];
  __shared__ float red[12];
  const int tid = threadIdx.x;
  const int b = blockIdx.x >> 2, m = blockIdx.x & 3;
  const float rr = x[b * 8 + m], ph = x[b * 8 + 4 + m];
  float sn, cs;
  sincosf(ph, &sn, &cs);
  const c32 alpha = make_float2(rr * cs, rr * sn);
  for (int e = tid; e < 144; e += 64) A[e] = CZERO;
  __syncthreads();
  if (tid < 11) {
    float sq = sqrtf((float)(tid + 1));
    A[(tid + 1) * 12 + tid] = make_float2(alpha.x * sq, alpha.y * sq);
    A[tid * 12 + tid + 1] = make_float2(-alpha.x * sq, alpha.y * sq);
  }
  __syncthreads();
  small_expm(A, S, P, T, red, 12, tid);
  if (tid < 12) c0[(size_t)blockIdx.x * 12 + tid] = S[tid * 12];
}

// ---------------- prep: beamsplitter sector blocks (direction-arranged) ----------------
__global__ __launch_bounds__(64) void prep_bs(const float* __restrict__ th1, const float* __restrict__ ph1,
                                              const float* __restrict__ th2, const float* __restrict__ ph2,
                                              c32* __restrict__ BS) {
  __shared__ c32 A[144], S[144], P[144], T[144];
  __shared__ float red[12];
  const int tid = threadIdx.x;
  const int g = blockIdx.x / 23, N = blockIdx.x % 23;
  const int l = g / 12, rem = g % 12, w = rem / 6, gi = rem % 6;
  const float th = (w ? th2 : th1)[l * 6 + gi];
  const float ph = (w ? ph2 : ph1)[l * 6 + gi];
  const int lo = (N > 11) ? (N - 11) : 0;
  const int sz = (N <= 11) ? (N + 1) : (23 - N);
  float sn, cs;
  sincosf(ph, &sn, &cs);
  for (int e = tid; e < sz * sz; e += 64) A[e] = CZERO;
  __syncthreads();
  if (tid + 1 < sz) {
    int t = tid + 1;
    float s1 = th * sqrtf((float)((lo + t) * (N - lo - t + 1)));
    A[(t - 1) * sz + t] = make_float2(cs * s1, sn * s1);
    A[t * sz + t - 1] = make_float2(-cs * s1, sn * s1);
  }
  __syncthreads();
  small_expm(A, S, P, T, red, sz, tid);
  c32* dst = BS + (size_t)g * 1156 + d_secoff[N];
  const bool upSec = (N <= 11);
  for (int e = tid; e < sz * sz; e += 64) {
    int p = e / sz, q = e - p * sz;
    int qs = upSec ? q : (sz - 1 - q);
    dst[p * sz + q] = S[p * sz + qs];
  }
}

// ---------------- prep: per-mode composites P1 = S*R1, P2 = K*Disp*R2 ----------------
__global__ __launch_bounds__(64) void prep_p(const float* __restrict__ r_, const float* __restrict__ phir,
                                             const float* __restrict__ vphi1,
                                             const float* __restrict__ a_, const float* __restrict__ phia,
                                             const float* __restrict__ vphi2, const float* __restrict__ kk,
                                             c32* __restrict__ P1, c32* __restrict__ P2) {
  __shared__ c32 A[144], S[144], P[144], T[144];
  __shared__ float red[12];
  const int tid = threadIdx.x;
  const int which = blockIdx.x >> 3, lm = blockIdx.x & 7;
  for (int e = tid; e < 144; e += 64) A[e] = CZERO;
  __syncthreads();
  if (which == 0) {
    const float rv = r_[lm], pv = phir[lm];
    float sn, cs;
    sincosf(pv, &sn, &cs);
    const c32 z = make_float2(rv * cs, rv * sn);
    if (tid < 10) {
      float sq = 0.5f * sqrtf((float)((tid + 1) * (tid + 2)));
      A[tid * 12 + tid + 2] = make_float2(z.x * sq, -z.y * sq);
      A[(tid + 2) * 12 + tid] = make_float2(-z.x * sq, -z.y * sq);
    }
  } else {
    const float av = a_[lm], pv = phia[lm];
    float sn, cs;
    sincosf(pv, &sn, &cs);
    const c32 alpha = make_float2(av * cs, av * sn);
    if (tid < 11) {
      float sq = sqrtf((float)(tid + 1));
      A[(tid + 1) * 12 + tid] = make_float2(alpha.x * sq, alpha.y * sq);
      A[tid * 12 + tid + 1] = make_float2(-alpha.x * sq, alpha.y * sq);
    }
  }
  __syncthreads();
  small_expm(A, S, P, T, red, 12, tid);
  if (which == 0) {
    const float vp = vphi1[lm];
    for (int e = tid; e < 144; e += 64) {
      int j = e % 12;
      float sn, cs;
      sincosf(vp * (float)j, &sn, &cs);
      P1[(size_t)lm * 144 + e] = cmul(S[e], make_float2(cs, sn));
    }
  } else {
    const float vp = vphi2[lm], kv = kk[lm];
    for (int e = tid; e < 144; e += 64) {
      int i = e / 12, j = e % 12;
      float sn1, cs1, sn2, cs2;
      sincosf(vp * (float)j, &sn1, &cs1);
      float ang = kv * (float)i;
      ang *= (float)i;
      sincosf(ang, &sn2, &cs2);
      P2[(size_t)lm * 144 + e] = cmul(make_float2(cs2, sn2), cmul(S[e], make_float2(cs1, sn1)));
    }
  }
}

// ---------------- fused pass over modes {1,2,3}: BS(2,3) -> BS(1,2) -> U1 -> U2 -> U3 ----------------
// Slab (b,n0) of 1728 c32; LDS [144 rows][15]. ALL 256 threads compute:
// task = (output element-row, spectator half/col-pair), 864 tasks per pass.
__global__ __launch_bounds__(256) void k123_kernel(
    c32* __restrict__ psi,
    const c32* __restrict__ gbs23, const c32* __restrict__ gbs12,
    const c32* __restrict__ gu1, const c32* __restrict__ gu2, const c32* __restrict__ gu3) {
  __shared__ c32 bufA[2160];
  __shared__ c32 bufB[2160];
  __shared__ c32 gate[1168];
  __shared__ c32 gV1[144], gV2[144], gV3t[144];
  const int tid = threadIdx.x;
  if (gu1) for (int e = tid; e < 144; e += 256) gV1[e] = gu1[e];
  if (gu2) for (int e = tid; e < 144; e += 256) gV2[e] = gu2[e];
  if (gu3) for (int e = tid; e < 144; e += 256) gV3t[(e % 12) * 12 + e / 12] = gu3[e]; // transposed
  for (int e = tid; e < 1156; e += 256) gate[e] = gbs23[e];
  c32* slab = psi + (size_t)blockIdx.x * 1728;
  for (int e = tid; e < 1728; e += 256) {
    int row = e / 12, col = e - 12 * row;
    bufA[ST * row + col] = slab[e];
  }
  __syncthreads();
  // pass 1: BS(2,3) — pattern (n2,n3) inside each 180-strided n1-block; task=(pattern r, n1-pair h)
  for (int tt = tid; tt < 864; tt += 256) {
    const int h = tt / 144, r = tt - 144 * h;
    const RM m = rmeta(r);
    const int b0 = 360 * h, b1 = b0 + 180;
    c32 acc0 = CZERO, acc1 = CZERO;
    int pos = m.a0;
#pragma unroll
    for (int t = 0; t < 12; ++t) {
      c32 g = gate[m.goff + t];
      if (t >= m.sz) g = CZERO;
      acc0 = cfma(g, bufA[b0 + pos], acc0);
      acc1 = cfma(g, bufA[b1 + pos], acc1);
      pos += m.da;
    }
    const int wp = ST * (r / 12) + (r - 12 * (r / 12));
    bufB[b0 + wp] = acc0;
    bufB[b1 + wp] = acc1;
  }
  __syncthreads();
  for (int e = tid; e < 1156; e += 256) gate[e] = gbs12[e];
  __syncthreads();
  // pass 2: BS(1,2) — pattern rows (n1,n2); task=(out-row r, col-pair c)
  for (int tt = tid; tt < 864; tt += 256) {
    const int r = tt / 6, c = tt - 6 * r;
    const RM m = rmeta(r);
    c32 acc0 = CZERO, acc1 = CZERO;
    int rho = m.r0;
#pragma unroll
    for (int t = 0; t < 12; ++t) {
      c32 g = gate[m.goff + t];
      if (t >= m.sz) g = CZERO;
      const int a = ST * rho + 2 * c;
      acc0 = cfma(g, bufB[a], acc0);
      acc1 = cfma(g, bufB[a + 1], acc1);
      rho += m.dr;
    }
    const int w = ST * r + 2 * c;
    bufA[w] = acc0;
    bufA[w + 1] = acc1;
  }
  c32* cur = bufA;
  c32* nxt = bufB;
  if (gu1) {  // U1 on n1: out row 12i+n2 reads rows 12j+n2
    __syncthreads();
    for (int tt = tid; tt < 864; tt += 256) {
      const int r = tt / 6, c = tt - 6 * r;
      const int i = r / 12, n2 = r - 12 * i;
      c32 acc0 = CZERO, acc1 = CZERO;
#pragma unroll
      for (int j = 0; j < 12; ++j) {
        c32 g = gV1[i * 12 + j];
        const int a = 180 * j + ST * n2 + 2 * c;
        acc0 = cfma(g, cur[a], acc0);
        acc1 = cfma(g, cur[a + 1], acc1);
      }
      const int w = ST * r + 2 * c;
      nxt[w] = acc0;
      nxt[w + 1] = acc1;
    }
    c32* t_ = cur; cur = nxt; nxt = t_;
  }
  if (gu2) {  // U2 on n2: out row 12n1+i reads rows 12n1+j
    __syncthreads();
    for (int tt = tid; tt < 864; tt += 256) {
      const int r = tt / 6, c = tt - 6 * r;
      const int n1 = r / 12, i = r - 12 * n1;
      c32 acc0 = CZERO, acc1 = CZERO;
#pragma unroll
      for (int j = 0; j < 12; ++j) {
        c32 g = gV2[i * 12 + j];
        const int a = 180 * n1 + ST * j + 2 * c;
        acc0 = cfma(g, cur[a], acc0);
        acc1 = cfma(g, cur[a + 1], acc1);
      }
      const int w = ST * r + 2 * c;
      nxt[w] = acc0;
      nxt[w + 1] = acc1;
    }
    c32* t_ = cur; cur = nxt; nxt = t_;
  }
  if (gu3) {  // U3 on n3: task=(row r, out col-pair co); transposed gate reads
    __syncthreads();
    for (int tt = tid; tt < 864; tt += 256) {
      const int r = tt / 6, co = tt - 6 * r;
      const int base = ST * r;
      c32 s0 = CZERO, s1 = CZERO;
#pragma unroll
      for (int j = 0; j < 12; ++j) {
        c32 v = cur[base + j];
        s0 = cfma(gV3t[12 * j + 2 * co], v, s0);
        s1 = cfma(gV3t[12 * j + 2 * co + 1], v, s1);
      }
      nxt[base + 2 * co] = s0;
      nxt[base + 2 * co + 1] = s1;
    }
    c32* t_ = cur; cur = nxt; nxt = t_;
  }
  __syncthreads();
  for (int e = tid; e < 1728; e += 256) {
    int row = e / 12, col = e - 12 * row;
    slab[e] = cur[ST * row + col];
  }
}

// ---------------- fused pass over modes {0,1}: [init] -> U0 -> BS(0,1) ----------------
// Tile = 144 (n0,n1)-rows x 16 flat (n2,n3)-cols; LDS [144][17]. 1152 tasks/pass.
__global__ __launch_bounds__(256) void k01_kernel(
    c32* __restrict__ psi, const c32* __restrict__ c0,
    const c32* __restrict__ gu0, const c32* __restrict__ gbs) {
  __shared__ c32 bufA[2448];
  __shared__ c32 bufB[2448];
  __shared__ c32 gate[1168];
  __shared__ c32 g0v[144];
  __shared__ c32 cv[4][12];
  const int tid = threadIdx.x;
  const int b = blockIdx.x / 9, t = blockIdx.x % 9;
  if (gu0) for (int e = tid; e < 144; e += 256) g0v[e] = gu0[e];
  if (gbs) for (int e = tid; e < 1156; e += 256) gate[e] = gbs[e];
  c32* gbase = psi + (size_t)b * D4 + t * 16;
  if (c0) {
    if (tid < 48) cv[tid / 12][tid % 12] = c0[(size_t)b * 48 + tid];
    __syncthreads();
    for (int e = tid; e < 2304; e += 256) {
      int row = e >> 4, q = e & 15;
      int cc = 16 * t + q, n2 = cc / 12, n3 = cc - 12 * n2;
      bufA[KP * row + q] =
          cmul(cmul(cv[0][row / 12], cv[1][row % 12]), cmul(cv[2][n2], cv[3][n3]));
    }
  } else {
    for (int e = tid; e < 2304; e += 256) {
      int row = e >> 4, q = e & 15;
      bufA[KP * row + q] = gbase[(size_t)row * 144 + q];
    }
  }
  __syncthreads();
  c32* cur = bufA;
  c32* nxt = bufB;
  if (gu0) {  // U0 on n0: out row 12i+n1 reads rows 12j+n1
    for (int tt = tid; tt < 1152; tt += 256) {
      const int r = tt >> 3, c = tt & 7;
      const int i = r / 12, n1 = r - 12 * i;
      c32 acc0 = CZERO, acc1 = CZERO;
#pragma unroll
      for (int j = 0; j < 12; ++j) {
        c32 g = g0v[i * 12 + j];
        const int a = 204 * j + KP * n1 + 2 * c;
        acc0 = cfma(g, cur[a], acc0);
        acc1 = cfma(g, cur[a + 1], acc1);
      }
      const int w = KP * r + 2 * c;
      nxt[w] = acc0;
      nxt[w + 1] = acc1;
    }
    c32* t_ = cur; cur = nxt; nxt = t_;
    __syncthreads();
  }
  if (gbs) {  // BS(0,1): pattern rows (n0,n1)
    for (int tt = tid; tt < 1152; tt += 256) {
      const int r = tt >> 3, c = tt & 7;
      const RM m = rmeta(r);
      c32 acc0 = CZERO, acc1 = CZERO;
      int rho = m.r0;
#pragma unroll
      for (int tk = 0; tk < 12; ++tk) {
        c32 g = gate[m.goff + tk];
        if (tk >= m.sz) g = CZERO;
        const int a = KP * rho + 2 * c;
        acc0 = cfma(g, cur[a], acc0);
        acc1 = cfma(g, cur[a + 1], acc1);
        rho += m.dr;
      }
      const int w = KP * r + 2 * c;
      nxt[w] = acc0;
      nxt[w + 1] = acc1;
    }
    c32* t_ = cur; cur = nxt; nxt = t_;
    __syncthreads();
  }
  for (int e = tid; e < 2304; e += 256) {
    int row = e >> 4, q = e & 15;
    gbase[(size_t)row * 144 + q] = cur[KP * row + q];
  }
}

// ---------------- expvals: <X_m> = sum 2*sqrt(n+1)*Re(conj(psi_n) psi_{n+1}) ----------------
__global__ __launch_bounds__(256) void expval_kernel(const c32* __restrict__ psi, float* __restrict__ out) {
  __shared__ float red[1024];
  __shared__ float sq2[12];
  const int tid = threadIdx.x, b = blockIdx.x;
  if (tid < 12) sq2[tid] = 2.f * sqrtf((float)(tid + 1));
  __syncthreads();
  const c32* base = psi + (size_t)b * D4;
  float a0 = 0.f, a1 = 0.f, a2 = 0.f, a3 = 0.f;
  for (int e = tid; e < D4; e += 256) {
    c32 p = base[e];
    int n3 = e % 12, t = e / 12;
    int n2 = t % 12; t /= 12;
    int n1 = t % 12, n0 = t / 12;
    if (n3 < 11) { c32 q = base[e + 1];    a3 = fmaf(sq2[n3], fmaf(p.x, q.x, p.y * q.y), a3); }
    if (n2 < 11) { c32 q = base[e + 12];   a2 = fmaf(sq2[n2], fmaf(p.x, q.x, p.y * q.y), a2); }
    if (n1 < 11) { c32 q = base[e + 144];  a1 = fmaf(sq2[n1], fmaf(p.x, q.x, p.y * q.y), a1); }
    if (n0 < 11) { c32 q = base[e + 1728]; a0 = fmaf(sq2[n0], fmaf(p.x, q.x, p.y * q.y), a0); }
  }
  red[tid * 4 + 0] = a0; red[tid * 4 + 1] = a1; red[tid * 4 + 2] = a2; red[tid * 4 + 3] = a3;
  __syncthreads();
  for (int s = 128; s > 0; s >>= 1) {
    if (tid < s) {
      red[tid * 4 + 0] += red[(tid + s) * 4 + 0];
      red[tid * 4 + 1] += red[(tid + s) * 4 + 1];
      red[tid * 4 + 2] += red[(tid + s) * 4 + 2];
      red[tid * 4 + 3] += red[(tid + s) * 4 + 3];
    }
    __syncthreads();
  }
  if (tid < 4) out[b * 4 + tid] = red[tid];
}

extern "C" void kernel_launch(void* const* d_in, const int* in_sizes, int n_in,
                              void* d_out, int out_size, void* d_ws, size_t ws_size,
                              hipStream_t stream) {
  const float* x      = (const float*)d_in[0];
  const float* theta1 = (const float*)d_in[1];
  const float* phi1   = (const float*)d_in[2];
  const float* vphi1  = (const float*)d_in[3];
  const float* r_     = (const float*)d_in[4];
  const float* phir   = (const float*)d_in[5];
  const float* theta2 = (const float*)d_in[6];
  const float* phi2   = (const float*)d_in[7];
  const float* vphi2  = (const float*)d_in[8];
  const float* a_     = (const float*)d_in[9];
  const float* phia   = (const float*)d_in[10];
  const float* kk     = (const float*)d_in[11];
  float* out = (float*)d_out;

  // workspace layout (bytes)
  const size_t PSI_OFF = 0;                              // 1024*20736*8
  const size_t C0_OFF  = 169869312;                      // 1024*4*12*8
  const size_t P1_OFF  = C0_OFF + 393216;
  const size_t P2_OFF  = P1_OFF + 9216;
  const size_t BS_OFF  = P2_OFF + 9216;                  // 24*1156*8
  const size_t NEED    = BS_OFF + 221952;
  if (ws_size < NEED) return;

  char* ws = (char*)d_ws;
  c32* psi = (c32*)(ws + PSI_OFF);
  c32* c0  = (c32*)(ws + C0_OFF);
  c32* P1  = (c32*)(ws + P1_OFF);
  c32* P2  = (c32*)(ws + P2_OFF);
  c32* BS  = (c32*)(ws + BS_OFF);

  prep_disp<<<dim3(4096), dim3(64), 0, stream>>>(x, c0);
  prep_bs<<<dim3(552), dim3(64), 0, stream>>>(theta1, phi1, theta2, phi2, BS);
  prep_p<<<dim3(16), dim3(64), 0, stream>>>(r_, phir, vphi1, a_, phia, vphi2, kk, P1, P2);

  for (int l = 0; l < 2; ++l) {
    c32* bsl = BS + (size_t)l * 12 * 1156;
    const c32* c0arg = (l == 0) ? c0 : (const c32*)nullptr;
    const c32* u0pre = (l == 0) ? (const c32*)nullptr : (const c32*)(P2 + (size_t)(l - 1) * 4 * 144);
    // interferometer 1: Clements order (0,1),(2,3),(1,2),(0,1),(2,3),(1,2)
    k01_kernel<<<dim3(9216), dim3(256), 0, stream>>>(psi, c0arg, u0pre, bsl + 0 * 1156);
    k123_kernel<<<dim3(12288), dim3(256), 0, stream>>>(psi, bsl + 1 * 1156, bsl + 2 * 1156,
                                                       nullptr, nullptr, nullptr);
    k01_kernel<<<dim3(9216), dim3(256), 0, stream>>>(psi, nullptr, nullptr, bsl + 3 * 1156);
    k123_kernel<<<dim3(12288), dim3(256), 0, stream>>>(psi, bsl + 4 * 1156, bsl + 5 * 1156,
                                                       P1 + (size_t)(l * 4 + 1) * 144,
                                                       P1 + (size_t)(l * 4 + 2) * 144,
                                                       P1 + (size_t)(l * 4 + 3) * 144);
    // interferometer 2 (P1 mode-0 composite rides along before its first BS(0,1))
    k01_kernel<<<dim3(9216), dim3(256), 0, stream>>>(psi, nullptr, P1 + (size_t)(l * 4 + 0) * 144, bsl + 6 * 1156);
    k123_kernel<<<dim3(12288), dim3(256), 0, stream>>>(psi, bsl + 7 * 1156, bsl + 8 * 1156,
                                                       nullptr, nullptr, nullptr);
    k01_kernel<<<dim3(9216), dim3(256), 0, stream>>>(psi, nullptr, nullptr, bsl + 9 * 1156);
    k123_kernel<<<dim3(12288), dim3(256), 0, stream>>>(psi, bsl + 10 * 1156, bsl + 11 * 1156,
                                                       P2 + (size_t)(l * 4 + 1) * 144,
                                                       P2 + (size_t)(l * 4 + 2) * 144,
                                                       P2 + (size_t)(l * 4 + 3) * 144);
  }
  // final pending mode-0 composite from layer 2
  k01_kernel<<<dim3(9216), dim3(256), 0, stream>>>(psi, nullptr, P2 + (size_t)(1 * 4 + 0) * 144, nullptr);
  expval_kernel<<<dim3(1024), dim3(256), 0, stream>>>(psi, out);
}

// Round 8
// 2178.806 us; speedup vs baseline: 1.5735x; 1.5735x over previous
//
#include <hip/hip_runtime.h>
#include <math.h>

#define D4 20736
#define ST 14    // k123 LDS row stride (c32), 112B
#define SST 168  // 12*ST: spectator stride for bs23
#define KP 18    // k01 LDS row stride (c32), 144B

typedef float2 c32;

__device__ __forceinline__ c32 cmul(c32 a, c32 b) {
  return make_float2(a.x * b.x - a.y * b.y, a.x * b.y + a.y * b.x);
}
__device__ __forceinline__ c32 cfma(c32 a, c32 b, c32 acc) {
  acc.x = fmaf(a.x, b.x, fmaf(-a.y, b.y, acc.x));
  acc.y = fmaf(a.x, b.y, fmaf(a.y, b.x, acc.y));
  return acc;
}
__device__ __forceinline__ c32 get2(const float4* w, int n) {
  float4 q = w[n >> 1];
  return (n & 1) ? make_float2(q.z, q.w) : make_float2(q.x, q.y);
}
__device__ __forceinline__ float4 pack2(c32 a, c32 b) {
  return make_float4(a.x, a.y, b.x, b.y);
}
#define CZERO make_float2(0.f, 0.f)

// sector offsets: secoff[N] = sum_{n<N} sz(n)^2
__constant__ int d_secoff[24] = {0,1,5,14,30,55,91,140,204,285,385,506,650,
                                 771,871,952,1016,1065,1101,1126,1142,1151,1155,1156};

struct RM { int goff, sz, a0, da, r0, dr; };
// metadata for output pattern-row r=(i,j); a-walk in ST-flat units (bs23),
// r-walk in row units. Down-sectors iterate descending (gates column-reversed).
__device__ __forceinline__ RM rmeta(int r) {
  const int i = r / 12, j = r - 12 * i, N = i + j;
  const bool up = (N <= 11);
  RM m;
  m.sz = (up ? N : 22 - N) + 1;
  const int lo = up ? 0 : (N - 11);
  m.goff = d_secoff[N] + (i - lo) * m.sz;
  m.a0 = up ? N : (143 + N);
  m.da = up ? 13 : -13;
  m.r0 = up ? N : (121 + N);
  m.dr = up ? 11 : -11;
  return m;
}

// ---------------- small matrix expm (LDS, 64-thread block) ----------------
__device__ void small_expm(c32* A, c32* S, c32* P, c32* T, float* red, int sz, int tid) {
  const int n2 = sz * sz;
  if (tid < sz) {
    float s = 0.f;
    for (int j = 0; j < sz; ++j) { c32 v = A[tid * sz + j]; s += sqrtf(fmaf(v.x, v.x, v.y * v.y)); }
    red[tid] = s;
  }
  __syncthreads();
  float nrm = 0.f;
  for (int i = 0; i < sz; ++i) nrm = fmaxf(nrm, red[i]);
  int sp = 0;
  while (nrm > 0.35f && sp < 24) { nrm *= 0.5f; ++sp; }
  const float scale = ldexpf(1.f, -sp);
  for (int e = tid; e < n2; e += 64) { A[e].x *= scale; A[e].y *= scale; }
  __syncthreads();
  for (int e = tid; e < n2; e += 64) {
    c32 a = A[e];
    P[e] = a;
    if ((e / sz) == (e % sz)) a.x += 1.f;
    S[e] = a;
  }
  __syncthreads();
  for (int k = 2; k <= 12; ++k) {
    const float inv = 1.f / (float)k;
    for (int e = tid; e < n2; e += 64) {
      int i = e / sz, j = e - i * sz;
      c32 acc = CZERO;
      for (int q = 0; q < sz; ++q) acc = cfma(P[i * sz + q], A[q * sz + j], acc);
      acc.x *= inv; acc.y *= inv;
      T[e] = acc;
    }
    __syncthreads();
    for (int e = tid; e < n2; e += 64) {
      c32 t = T[e];
      P[e] = t;
      S[e].x += t.x; S[e].y += t.y;
    }
    __syncthreads();
  }
  for (int q = 0; q < sp; ++q) {
    for (int e = tid; e < n2; e += 64) {
      int i = e / sz, j = e - i * sz;
      c32 acc = CZERO;
      for (int w = 0; w < sz; ++w) acc = cfma(S[i * sz + w], S[w * sz + j], acc);
      T[e] = acc;
    }
    __syncthreads();
    for (int e = tid; e < n2; e += 64) S[e] = T[e];
    __syncthreads();
  }
}

// ---------------- prep: per-batch displacement encoding (store col 0) ----------------
__global__ __launch_bounds__(64) void prep_disp(const float* __restrict__ x, c32* __restrict__ c0) {
  __shared__ c32 A[144], S[144], P[144], T[144];
  __shared__ float red[12];
  const int tid = threadIdx.x;
  const int b = blockIdx.x >> 2, m = blockIdx.x & 3;
  const float rr = x[b * 8 + m], ph = x[b * 8 + 4 + m];
  float sn, cs;
  sincosf(ph, &sn, &cs);
  const c32 alpha = make_float2(rr * cs, rr * sn);
  for (int e = tid; e < 144; e += 64) A[e] = CZERO;
  __syncthreads();
  if (tid < 11) {
    float sq = sqrtf((float)(tid + 1));
    A[(tid + 1) * 12 + tid] = make_float2(alpha.x * sq, alpha.y * sq);
    A[tid * 12 + tid + 1] = make_float2(-alpha.x * sq, alpha.y * sq);
  }
  __syncthreads();
  small_expm(A, S, P, T, red, 12, tid);
  if (tid < 12) c0[(size_t)blockIdx.x * 12 + tid] = S[tid * 12];
}

// ---------------- prep: beamsplitter sector blocks (direction-arranged) ----------------
__global__ __launch_bounds__(64) void prep_bs(const float* __restrict__ th1, const float* __restrict__ ph1,
                                              const float* __restrict__ th2, const float* __restrict__ ph2,
                                              c32* __restrict__ BS) {
  __shared__ c32 A[144], S[144], P[144], T[144];
  __shared__ float red[12];
  const int tid = threadIdx.x;
  const int g = blockIdx.x / 23, N = blockIdx.x % 23;
  const int l = g / 12, rem = g % 12, w = rem / 6, gi = rem % 6;
  const float th = (w ? th2 : th1)[l * 6 + gi];
  const float ph = (w ? ph2 : ph1)[l * 6 + gi];
  const int lo = (N > 11) ? (N - 11) : 0;
  const int sz = (N <= 11) ? (N + 1) : (23 - N);
  float sn, cs;
  sincosf(ph, &sn, &cs);
  for (int e = tid; e < sz * sz; e += 64) A[e] = CZERO;
  __syncthreads();
  if (tid + 1 < sz) {
    int t = tid + 1;
    float s1 = th * sqrtf((float)((lo + t) * (N - lo - t + 1)));
    A[(t - 1) * sz + t] = make_float2(cs * s1, sn * s1);
    A[t * sz + t - 1] = make_float2(-cs * s1, sn * s1);
  }
  __syncthreads();
  small_expm(A, S, P, T, red, sz, tid);
  c32* dst = BS + (size_t)g * 1156 + d_secoff[N];
  const bool upSec = (N <= 11);
  for (int e = tid; e < sz * sz; e += 64) {
    int p = e / sz, q = e - p * sz;
    int qs = upSec ? q : (sz - 1 - q);
    dst[p * sz + q] = S[p * sz + qs];
  }
}

// ---------------- prep: per-mode composites P1 = S*R1, P2 = K*Disp*R2 ----------------
__global__ __launch_bounds__(64) void prep_p(const float* __restrict__ r_, const float* __restrict__ phir,
                                             const float* __restrict__ vphi1,
                                             const float* __restrict__ a_, const float* __restrict__ phia,
                                             const float* __restrict__ vphi2, const float* __restrict__ kk,
                                             c32* __restrict__ P1, c32* __restrict__ P2) {
  __shared__ c32 A[144], S[144], P[144], T[144];
  __shared__ float red[12];
  const int tid = threadIdx.x;
  const int which = blockIdx.x >> 3, lm = blockIdx.x & 7;
  for (int e = tid; e < 144; e += 64) A[e] = CZERO;
  __syncthreads();
  if (which == 0) {
    const float rv = r_[lm], pv = phir[lm];
    float sn, cs;
    sincosf(pv, &sn, &cs);
    const c32 z = make_float2(rv * cs, rv * sn);
    if (tid < 10) {
      float sq = 0.5f * sqrtf((float)((tid + 1) * (tid + 2)));
      A[tid * 12 + tid + 2] = make_float2(z.x * sq, -z.y * sq);
      A[(tid + 2) * 12 + tid] = make_float2(-z.x * sq, -z.y * sq);
    }
  } else {
    const float av = a_[lm], pv = phia[lm];
    float sn, cs;
    sincosf(pv, &sn, &cs);
    const c32 alpha = make_float2(av * cs, av * sn);
    if (tid < 11) {
      float sq = sqrtf((float)(tid + 1));
      A[(tid + 1) * 12 + tid] = make_float2(alpha.x * sq, alpha.y * sq);
      A[tid * 12 + tid + 1] = make_float2(-alpha.x * sq, alpha.y * sq);
    }
  }
  __syncthreads();
  small_expm(A, S, P, T, red, 12, tid);
  if (which == 0) {
    const float vp = vphi1[lm];
    for (int e = tid; e < 144; e += 64) {
      int j = e % 12;
      float sn, cs;
      sincosf(vp * (float)j, &sn, &cs);
      P1[(size_t)lm * 144 + e] = cmul(S[e], make_float2(cs, sn));
    }
  } else {
    const float vp = vphi2[lm], kv = kk[lm];
    for (int e = tid; e < 144; e += 64) {
      int i = e / 12, j = e % 12;
      float sn1, cs1, sn2, cs2;
      sincosf(vp * (float)j, &sn1, &cs1);
      float ang = kv * (float)i;
      ang *= (float)i;
      sincosf(ang, &sn2, &cs2);
      P2[(size_t)lm * 144 + e] = cmul(make_float2(cs2, sn2), cmul(S[e], make_float2(cs1, sn1)));
    }
  }
}

// ---------------- fused pass over modes {1,2,3}: BS(2,3) -> BS(1,2) -> U1 -> U2 -> U3 ----------------
// Slab (b,n0) of 1728 c32; single in-place LDS buffer [144 rows][14].
// Each pass: compute-to-regs -> sync -> write-back -> sync.  5 blocks/CU.
__global__ __launch_bounds__(256, 5) void k123_kernel(
    c32* __restrict__ psi,
    const c32* __restrict__ gbs23, const c32* __restrict__ gbs12,
    const c32* __restrict__ gu1, const c32* __restrict__ gu2, const c32* __restrict__ gu3) {
  __shared__ __align__(16) c32 buf[2016];
  __shared__ c32 gate[1168];
  __shared__ c32 gV1[144], gV2[144], gV3[144];
  const int tid = threadIdx.x;
  if (gu1) for (int e = tid; e < 144; e += 256) gV1[e] = gu1[e];
  if (gu2) for (int e = tid; e < 144; e += 256) gV2[e] = gu2[e];
  if (gu3) for (int e = tid; e < 144; e += 256) gV3[e] = gu3[e];
  for (int e = tid; e < 1156; e += 256) gate[e] = gbs23[e];
  c32* slab = psi + (size_t)blockIdx.x * 1728;
  for (int v = tid; v < 864; v += 256) {
    float4 q = ((const float4*)slab)[v];
    *((float4*)buf + 7 * (v / 6) + (v % 6)) = q;
  }
  __syncthreads();
  const int r = tid;
  RM m;
  if (r < 144) m = rmeta(r);
  c32 acc[12];
  // ---- pass 1: BS(2,3): pattern (n2,n3) within each 168-stride n1-block
  if (r < 144) {
#pragma unroll
    for (int n = 0; n < 12; ++n) acc[n] = CZERO;
    int a = m.a0;
#pragma unroll
    for (int t = 0; t < 12; ++t) {
      c32 g = gate[m.goff + t];
      if (t >= m.sz) g = CZERO;
#pragma unroll
      for (int n = 0; n < 12; ++n) acc[n] = cfma(g, buf[SST * n + a], acc[n]);
      a += m.da;
    }
  }
  __syncthreads();
  if (r < 144) {
    const int wr = ST * (r / 12) + (r % 12);
#pragma unroll
    for (int n = 0; n < 12; ++n) buf[SST * n + wr] = acc[n];
  }
  for (int e = tid; e < 1156; e += 256) gate[e] = gbs12[e];  // reload during write phase
  __syncthreads();
  // ---- pass 2: BS(1,2): pattern rows (n1,n2), spectator n3 in-row (b128)
  if (r < 144) {
#pragma unroll
    for (int n = 0; n < 12; ++n) acc[n] = CZERO;
    int rho = m.r0;
#pragma unroll
    for (int t = 0; t < 12; ++t) {
      c32 g = gate[m.goff + t];
      if (t >= m.sz) g = CZERO;
      const float4* ip = (const float4*)buf + 7 * rho;
      float4 w[6];
#pragma unroll
      for (int q = 0; q < 6; ++q) w[q] = ip[q];
#pragma unroll
      for (int n = 0; n < 12; ++n) acc[n] = cfma(g, get2(w, n), acc[n]);
      rho += m.dr;
    }
  }
  __syncthreads();
  if (r < 144) {
    float4* op = (float4*)buf + 7 * r;
#pragma unroll
    for (int q = 0; q < 6; ++q) op[q] = pack2(acc[2 * q], acc[2 * q + 1]);
  }
  // ---- U1 on n1: out row 12i+n2 reads rows 12j+n2
  if (gu1) {
    __syncthreads();
    if (r < 144) {
      const int i = r / 12, n2 = r - 12 * (r / 12);
#pragma unroll
      for (int n = 0; n < 12; ++n) acc[n] = CZERO;
#pragma unroll
      for (int j = 0; j < 12; ++j) {
        c32 g = gV1[i * 12 + j];
        const float4* ip = (const float4*)buf + 7 * (12 * j + n2);
        float4 w[6];
#pragma unroll
        for (int q = 0; q < 6; ++q) w[q] = ip[q];
#pragma unroll
        for (int n = 0; n < 12; ++n) acc[n] = cfma(g, get2(w, n), acc[n]);
      }
    }
    __syncthreads();
    if (r < 144) {
      float4* op = (float4*)buf + 7 * r;
#pragma unroll
      for (int q = 0; q < 6; ++q) op[q] = pack2(acc[2 * q], acc[2 * q + 1]);
    }
  }
  // ---- U2 on n2: out row 12n1+i reads rows 12n1+j
  if (gu2) {
    __syncthreads();
    if (r < 144) {
      const int n1 = r / 12, i = r - 12 * (r / 12);
#pragma unroll
      for (int n = 0; n < 12; ++n) acc[n] = CZERO;
#pragma unroll
      for (int j = 0; j < 12; ++j) {
        c32 g = gV2[i * 12 + j];
        const float4* ip = (const float4*)buf + 7 * (12 * n1 + j);
        float4 w[6];
#pragma unroll
        for (int q = 0; q < 6; ++q) w[q] = ip[q];
#pragma unroll
        for (int n = 0; n < 12; ++n) acc[n] = cfma(g, get2(w, n), acc[n]);
      }
    }
    __syncthreads();
    if (r < 144) {
      float4* op = (float4*)buf + 7 * r;
#pragma unroll
      for (int q = 0; q < 6; ++q) op[q] = pack2(acc[2 * q], acc[2 * q + 1]);
    }
  }
  // ---- U3 on n3: purely in-row (thread owns its row; no cross-thread hazard)
  if (gu3) {
    __syncthreads();
    if (r < 144) {
      const float4* ip = (const float4*)buf + 7 * r;
      float4 wv[6];
#pragma unroll
      for (int q = 0; q < 6; ++q) wv[q] = ip[q];
      float4* op = (float4*)buf + 7 * r;
#pragma unroll
      for (int cpair = 0; cpair < 6; ++cpair) {
        c32 s0 = CZERO, s1 = CZERO;
#pragma unroll
        for (int j = 0; j < 12; ++j) {
          c32 v = get2(wv, j);
          s0 = cfma(gV3[(2 * cpair) * 12 + j], v, s0);
          s1 = cfma(gV3[(2 * cpair + 1) * 12 + j], v, s1);
        }
        op[cpair] = pack2(s0, s1);
      }
    }
  }
  __syncthreads();
  for (int v = tid; v < 864; v += 256) {
    ((float4*)slab)[v] = *((const float4*)buf + 7 * (v / 6) + (v % 6));
  }
}

// ---------------- fused pass over modes {0,1}: [init] -> U0 -> BS(0,1) ----------------
// Tile = 144 (n0,n1)-rows x 16 flat cols; single in-place LDS [144][18]. 5 blocks/CU.
__global__ __launch_bounds__(256, 5) void k01_kernel(
    c32* __restrict__ psi, const c32* __restrict__ c0,
    const c32* __restrict__ gu0, const c32* __restrict__ gbs) {
  __shared__ __align__(16) c32 buf[2592];
  __shared__ c32 gate[1168];
  __shared__ c32 g0v[144];
  __shared__ c32 cv[4][12];
  const int tid = threadIdx.x;
  const int b = blockIdx.x / 9, t = blockIdx.x % 9;
  if (gu0) for (int e = tid; e < 144; e += 256) g0v[e] = gu0[e];
  if (gbs) for (int e = tid; e < 1156; e += 256) gate[e] = gbs[e];
  c32* gbase = psi + (size_t)b * D4 + t * 16;
  if (c0) {
    if (tid < 48) cv[tid / 12][tid % 12] = c0[(size_t)b * 48 + tid];
    __syncthreads();
    for (int e = tid; e < 2304; e += 256) {
      int row = e >> 4, q = e & 15;
      int cc = 16 * t + q, n2 = cc / 12, n3 = cc - 12 * n2;
      buf[KP * row + q] =
          cmul(cmul(cv[0][row / 12], cv[1][row % 12]), cmul(cv[2][n2], cv[3][n3]));
    }
  } else {
    for (int e = tid; e < 1152; e += 256) {
      int row = e >> 3, q = e & 7;
      ((float4*)(buf + row * KP))[q] = ((const float4*)(gbase + (size_t)row * 144))[q];
    }
  }
  __syncthreads();
  const int r = tid;
  c32 acc[16];
  // ---- U0 on n0: out row 12i+n1 reads rows 12j+n1
  if (gu0) {
    if (r < 144) {
      const int i = r / 12, n1 = r - 12 * (r / 12);
#pragma unroll
      for (int n = 0; n < 16; ++n) acc[n] = CZERO;
#pragma unroll
      for (int j = 0; j < 12; ++j) {
        c32 g = g0v[i * 12 + j];
        const float4* ip = (const float4*)(buf + (12 * j + n1) * KP);
        float4 w[8];
#pragma unroll
        for (int q = 0; q < 8; ++q) w[q] = ip[q];
#pragma unroll
        for (int n = 0; n < 16; ++n) acc[n] = cfma(g, get2(w, n), acc[n]);
      }
    }
    __syncthreads();
    if (r < 144) {
      float4* op = (float4*)(buf + r * KP);
#pragma unroll
      for (int q = 0; q < 8; ++q) op[q] = pack2(acc[2 * q], acc[2 * q + 1]);
    }
    __syncthreads();
  }
  // ---- BS(0,1): pattern rows (n0,n1)
  if (gbs) {
    if (r < 144) {
      const RM m = rmeta(r);
#pragma unroll
      for (int n = 0; n < 16; ++n) acc[n] = CZERO;
      int rho = m.r0;
#pragma unroll
      for (int tk = 0; tk < 12; ++tk) {
        c32 g = gate[m.goff + tk];
        if (tk >= m.sz) g = CZERO;
        const float4* ip = (const float4*)(buf + rho * KP);
        float4 w[8];
#pragma unroll
        for (int q = 0; q < 8; ++q) w[q] = ip[q];
#pragma unroll
        for (int n = 0; n < 16; ++n) acc[n] = cfma(g, get2(w, n), acc[n]);
        rho += m.dr;
      }
    }
    __syncthreads();
    if (r < 144) {
      float4* op = (float4*)(buf + r * KP);
#pragma unroll
      for (int q = 0; q < 8; ++q) op[q] = pack2(acc[2 * q], acc[2 * q + 1]);
    }
    __syncthreads();
  }
  for (int e = tid; e < 1152; e += 256) {
    int row = e >> 3, q = e & 7;
    ((float4*)(gbase + (size_t)row * 144))[q] = ((const float4*)(buf + row * KP))[q];
  }
}

// ---------------- expvals: <X_m> = sum 2*sqrt(n+1)*Re(conj(psi_n) psi_{n+1}) ----------------
__global__ __launch_bounds__(256) void expval_kernel(const c32* __restrict__ psi, float* __restrict__ out) {
  __shared__ float red[1024];
  __shared__ float sq2[12];
  const int tid = threadIdx.x, b = blockIdx.x;
  if (tid < 12) sq2[tid] = 2.f * sqrtf((float)(tid + 1));
  __syncthreads();
  const c32* base = psi + (size_t)b * D4;
  float a0 = 0.f, a1 = 0.f, a2 = 0.f, a3 = 0.f;
  for (int e = tid; e < D4; e += 256) {
    c32 p = base[e];
    int n3 = e % 12, t = e / 12;
    int n2 = t % 12; t /= 12;
    int n1 = t % 12, n0 = t / 12;
    if (n3 < 11) { c32 q = base[e + 1];    a3 = fmaf(sq2[n3], fmaf(p.x, q.x, p.y * q.y), a3); }
    if (n2 < 11) { c32 q = base[e + 12];   a2 = fmaf(sq2[n2], fmaf(p.x, q.x, p.y * q.y), a2); }
    if (n1 < 11) { c32 q = base[e + 144];  a1 = fmaf(sq2[n1], fmaf(p.x, q.x, p.y * q.y), a1); }
    if (n0 < 11) { c32 q = base[e + 1728]; a0 = fmaf(sq2[n0], fmaf(p.x, q.x, p.y * q.y), a0); }
  }
  red[tid * 4 + 0] = a0; red[tid * 4 + 1] = a1; red[tid * 4 + 2] = a2; red[tid * 4 + 3] = a3;
  __syncthreads();
  for (int s = 128; s > 0; s >>= 1) {
    if (tid < s) {
      red[tid * 4 + 0] += red[(tid + s) * 4 + 0];
      red[tid * 4 + 1] += red[(tid + s) * 4 + 1];
      red[tid * 4 + 2] += red[(tid + s) * 4 + 2];
      red[tid * 4 + 3] += red[(tid + s) * 4 + 3];
    }
    __syncthreads();
  }
  if (tid < 4) out[b * 4 + tid] = red[tid];
}

extern "C" void kernel_launch(void* const* d_in, const int* in_sizes, int n_in,
                              void* d_out, int out_size, void* d_ws, size_t ws_size,
                              hipStream_t stream) {
  const float* x      = (const float*)d_in[0];
  const float* theta1 = (const float*)d_in[1];
  const float* phi1   = (const float*)d_in[2];
  const float* vphi1  = (const float*)d_in[3];
  const float* r_     = (const float*)d_in[4];
  const float* phir   = (const float*)d_in[5];
  const float* theta2 = (const float*)d_in[6];
  const float* phi2   = (const float*)d_in[7];
  const float* vphi2  = (const float*)d_in[8];
  const float* a_     = (const float*)d_in[9];
  const float* phia   = (const float*)d_in[10];
  const float* kk     = (const float*)d_in[11];
  float* out = (float*)d_out;

  // workspace layout (bytes)
  const size_t PSI_OFF = 0;                              // 1024*20736*8
  const size_t C0_OFF  = 169869312;                      // 1024*4*12*8
  const size_t P1_OFF  = C0_OFF + 393216;
  const size_t P2_OFF  = P1_OFF + 9216;
  const size_t BS_OFF  = P2_OFF + 9216;                  // 24*1156*8
  const size_t NEED    = BS_OFF + 221952;
  if (ws_size < NEED) return;

  char* ws = (char*)d_ws;
  c32* psi = (c32*)(ws + PSI_OFF);
  c32* c0  = (c32*)(ws + C0_OFF);
  c32* P1  = (c32*)(ws + P1_OFF);
  c32* P2  = (c32*)(ws + P2_OFF);
  c32* BS  = (c32*)(ws + BS_OFF);

  prep_disp<<<dim3(4096), dim3(64), 0, stream>>>(x, c0);
  prep_bs<<<dim3(552), dim3(64), 0, stream>>>(theta1, phi1, theta2, phi2, BS);
  prep_p<<<dim3(16), dim3(64), 0, stream>>>(r_, phir, vphi1, a_, phia, vphi2, kk, P1, P2);

  for (int l = 0; l < 2; ++l) {
    c32* bsl = BS + (size_t)l * 12 * 1156;
    const c32* c0arg = (l == 0) ? c0 : (const c32*)nullptr;
    const c32* u0pre = (l == 0) ? (const c32*)nullptr : (const c32*)(P2 + (size_t)(l - 1) * 4 * 144);
    // interferometer 1: Clements order (0,1),(2,3),(1,2),(0,1),(2,3),(1,2)
    k01_kernel<<<dim3(9216), dim3(256), 0, stream>>>(psi, c0arg, u0pre, bsl + 0 * 1156);
    k123_kernel<<<dim3(12288), dim3(256), 0, stream>>>(psi, bsl + 1 * 1156, bsl + 2 * 1156,
                                                       nullptr, nullptr, nullptr);
    k01_kernel<<<dim3(9216), dim3(256), 0, stream>>>(psi, nullptr, nullptr, bsl + 3 * 1156);
    k123_kernel<<<dim3(12288), dim3(256), 0, stream>>>(psi, bsl + 4 * 1156, bsl + 5 * 1156,
                                                       P1 + (size_t)(l * 4 + 1) * 144,
                                                       P1 + (size_t)(l * 4 + 2) * 144,
                                                       P1 + (size_t)(l * 4 + 3) * 144);
    // interferometer 2 (P1 mode-0 composite rides along before its first BS(0,1))
    k01_kernel<<<dim3(9216), dim3(256), 0, stream>>>(psi, nullptr, P1 + (size_t)(l * 4 + 0) * 144, bsl + 6 * 1156);
    k123_kernel<<<dim3(12288), dim3(256), 0, stream>>>(psi, bsl + 7 * 1156, bsl + 8 * 1156,
                                                       nullptr, nullptr, nullptr);
    k01_kernel<<<dim3(9216), dim3(256), 0, stream>>>(psi, nullptr, nullptr, bsl + 9 * 1156);
    k123_kernel<<<dim3(12288), dim3(256), 0, stream>>>(psi, bsl + 10 * 1156, bsl + 11 * 1156,
                                                       P2 + (size_t)(l * 4 + 1) * 144,
                                                       P2 + (size_t)(l * 4 + 2) * 144,
                                                       P2 + (size_t)(l * 4 + 3) * 144);
  }
  // final pending mode-0 composite from layer 2
  k01_kernel<<<dim3(9216), dim3(256), 0, stream>>>(psi, nullptr, P2 + (size_t)(1 * 4 + 0) * 144, nullptr);
  expval_kernel<<<dim3(1024), dim3(256), 0, stream>>>(psi, out);
}